// Round 1
// baseline (761.252 us; speedup 1.0000x reference)
//
#include <hip/hip_runtime.h>

#define HH 384
#define WW 384
#define CROP 7
#define OUTD 370
#define TILE 32
#define NTILE 12          // ceil(370/32)
#define RSZ 38            // TILE + 6 halo
#define SQ_LD 39          // +1 pad to break bank conflicts
#define NSHIFT 99
#define NPIX (4 * OUTD * OUTD)

// Separable 7x7 gaussian conv of the shifted squared-difference over one
// 32x32 output tile. Output D[j] for rows ty+8j, col tx. Exactly two
// __syncthreads per call; safe to call back-to-back (sq/tmp hazards covered
// by the post-fill and post-horizontal barriers).
__device__ __forceinline__ void conv_tile(
    const float* __restrict__ img, int iy0, int ix0, int sx, int sy,
    float* sq, float* tmp, int tid, int tx, int ty, float* D)
{
    const float G0 = 0.32465246735834974f;   // exp(-9/8)
    const float G1 = 0.6065306597126334f;    // exp(-4/8)
    const float G2 = 0.8824969025845955f;    // exp(-1/8)
    const float KS = 0.039788735772973836f;  // 1/(8*pi)

    // diffsq fill: (img[p] - img[p - (sy,sx) mod 384])^2 over 38x38 halo tile
    for (int i = tid; i < RSZ * RSZ; i += 256) {
        int r = i / RSZ;
        int c = i - r * RSZ;
        int mr = iy0 + r; mr = mr > (HH - 1) ? (HH - 1) : mr;  // clamp: partial tiles
        int mc = ix0 + c; mc = mc > (WW - 1) ? (WW - 1) : mc;
        int rr = mr - sy; if (rr < 0) rr += HH; if (rr >= HH) rr -= HH;
        int cc = mc - sx; if (cc < 0) cc += WW; if (cc >= WW) cc -= WW;
        float a = img[mr * WW + mc];
        float b = img[rr * WW + cc];
        float d = a - b;
        sq[r * SQ_LD + c] = d * d;
    }
    __syncthreads();
    // horizontal 7-tap
    for (int i = tid; i < RSZ * TILE; i += 256) {
        int r = i >> 5;
        int c = i & 31;
        const float* s = &sq[r * SQ_LD + c];
        tmp[i] = G0 * (s[0] + s[6]) + G1 * (s[1] + s[5]) + G2 * (s[2] + s[4]) + s[3];
    }
    __syncthreads();
    // vertical 7-tap
#pragma unroll
    for (int j = 0; j < 4; ++j) {
        int ry = ty + j * 8;
        const float* t = &tmp[ry * TILE + tx];
        float v = G0 * (t[0] + t[6 * TILE]) + G1 * (t[1 * TILE] + t[5 * TILE]) +
                  G2 * (t[2 * TILE] + t[4 * TILE]) + t[3 * TILE];
        D[j] = v * KS;
    }
}

// Stage 2: per (tile, batch, image) compute V = mean of 4 cardinal D + eps and
// minD over the 99 shifts. One owner block per pixel -> register min, no atomics.
extern "C" __global__ void __launch_bounds__(256)
mind_stage2(const float* __restrict__ pred, const float* __restrict__ gt,
            float* __restrict__ ws)
{
    __shared__ float sq[RSZ * SQ_LD];
    __shared__ float tmp[RSZ * TILE];
    const int tid = threadIdx.x;
    const int tx = tid & 31, ty = tid >> 5;
    const int b = blockIdx.y;
    const int z = blockIdx.z;
    const int oy0 = ((int)blockIdx.x / NTILE) * TILE;
    const int ox0 = ((int)blockIdx.x % NTILE) * TILE;
    const int iy0 = oy0 + CROP - 3;
    const int ix0 = ox0 + CROP - 3;
    const float* img = (z ? gt : pred) + (size_t)b * HH * WW;
    float* V = ws + (size_t)z * NPIX;
    float* M = ws + (size_t)(2 + z) * NPIX;

    float dmin[4] = {1e30f, 1e30f, 1e30f, 1e30f};
    float vsum[4] = {0.f, 0.f, 0.f, 0.f};
    float D[4];
    for (int s = 0; s < NSHIFT; ++s) {
        int t = (s < 55) ? s : s + 1;       // skip (0,0) at index 55
        int sx = t / 10 - 5;                // x outer loop in reference
        int sy = t - (t / 10) * 10 - 5;     // y inner
        conv_tile(img, iy0, ix0, sx, sy, sq, tmp, tid, tx, ty, D);
        const bool card = (sx * sx + sy * sy) == 1;
#pragma unroll
        for (int j = 0; j < 4; ++j) {
            dmin[j] = fminf(dmin[j], D[j]);
            if (card) vsum[j] += D[j];
        }
    }
#pragma unroll
    for (int j = 0; j < 4; ++j) {
        int oy = oy0 + ty + j * 8;
        int ox = ox0 + tx;
        if (oy < OUTD && ox < OUTD) {
            size_t idx = ((size_t)b * OUTD + oy) * OUTD + ox;
            V[idx] = vsum[j] * 0.25f + 1e-5f;
            M[idx] = dmin[j];
        }
    }
}

// Stage 3: recompute D per shift for both images, accumulate
// |exp((minDp-Dp)/Vp) - exp((minDg-Dg)/Vg)|, reduce, atomicAdd scaled mean.
extern "C" __global__ void __launch_bounds__(256)
mind_stage3(const float* __restrict__ pred, const float* __restrict__ gt,
            const float* __restrict__ ws, float* __restrict__ out)
{
    __shared__ float sq[RSZ * SQ_LD];
    __shared__ float tmp[RSZ * TILE];
    __shared__ float wred[4];
    const int tid = threadIdx.x;
    const int tx = tid & 31, ty = tid >> 5;
    const int b = blockIdx.y;
    const int oy0 = ((int)blockIdx.x / NTILE) * TILE;
    const int ox0 = ((int)blockIdx.x % NTILE) * TILE;
    const int iy0 = oy0 + CROP - 3;
    const int ix0 = ox0 + CROP - 3;
    const float* ip = pred + (size_t)b * HH * WW;
    const float* ig = gt + (size_t)b * HH * WW;
    const float* Vp = ws;
    const float* Vg = ws + (size_t)NPIX;
    const float* Mp = ws + (size_t)2 * NPIX;
    const float* Mg = ws + (size_t)3 * NPIX;

    float rvp[4], rvg[4], mp[4], mg[4];
    bool valid[4];
#pragma unroll
    for (int j = 0; j < 4; ++j) {
        int oy = oy0 + ty + j * 8;
        int ox = ox0 + tx;
        valid[j] = (oy < OUTD) && (ox < OUTD);
        if (valid[j]) {
            size_t idx = ((size_t)b * OUTD + oy) * OUTD + ox;
            rvp[j] = 1.0f / Vp[idx]; mp[j] = Mp[idx];
            rvg[j] = 1.0f / Vg[idx]; mg[j] = Mg[idx];
        } else {
            rvp[j] = 0.f; mp[j] = 0.f; rvg[j] = 0.f; mg[j] = 0.f;
        }
    }

    float acc = 0.f;
    float Dp[4], Dg[4];
    for (int s = 0; s < NSHIFT; ++s) {
        int t = (s < 55) ? s : s + 1;
        int sx = t / 10 - 5;
        int sy = t - (t / 10) * 10 - 5;
        conv_tile(ip, iy0, ix0, sx, sy, sq, tmp, tid, tx, ty, Dp);
        conv_tile(ig, iy0, ix0, sx, sy, sq, tmp, tid, tx, ty, Dg);
#pragma unroll
        for (int j = 0; j < 4; ++j) {
            if (valid[j]) {
                float ep = __expf((mp[j] - Dp[j]) * rvp[j]);
                float eg = __expf((mg[j] - Dg[j]) * rvg[j]);
                acc += fabsf(ep - eg);
            }
        }
    }

#pragma unroll
    for (int off = 32; off > 0; off >>= 1) acc += __shfl_down(acc, off, 64);
    const int lane = tid & 63, wv = tid >> 6;
    if (lane == 0) wred[wv] = acc;
    __syncthreads();
    if (tid == 0) {
        const float SC = (float)(1.0 / 54212400.0);  // 1/(4*370*370*99)
        atomicAdd(out, (wred[0] + wred[1] + wred[2] + wred[3]) * SC);
    }
}

extern "C" void kernel_launch(void* const* d_in, const int* in_sizes, int n_in,
                              void* d_out, int out_size, void* d_ws, size_t ws_size,
                              hipStream_t stream)
{
    (void)in_sizes; (void)n_in; (void)out_size; (void)ws_size;
    const float* pred = (const float*)d_in[0];
    const float* gt   = (const float*)d_in[1];
    float* out = (float*)d_out;
    float* ws  = (float*)d_ws;

    hipMemsetAsync(d_out, 0, sizeof(float), stream);  // async memset: graph-capture safe

    dim3 g2(NTILE * NTILE, 4, 2);
    mind_stage2<<<g2, 256, 0, stream>>>(pred, gt, ws);
    dim3 g3(NTILE * NTILE, 4, 1);
    mind_stage3<<<g3, 256, 0, stream>>>(pred, gt, ws, out);
}

// Round 2
// 363.920 us; speedup vs baseline: 2.0918x; 2.0918x over previous
//
#include <hip/hip_runtime.h>

#define HH 384
#define WW 384
#define OUTD 370
#define TILE 32
#define NTILE 12
#define LS 47            // image LDS tile extent AND stride (no pad)
#define FR 38            // diffsq fill extent (TILE + 6 conv halo)
#define SQLD 42          // sq stride: even (float2 align), 42%32=10 -> conflict-free chunks
#define TMLD 34          // tmp stride: even, 34%32=2 -> spread banks
#define NPIX (4 * OUTD * OUTD)
#define NSHIFT 99
#define NFU 722          // fill float2-pair units: 38*38/2

__device__ __forceinline__ void load_img_tile(const float* __restrict__ img,
                                              int oy0, int ox0, float* L, int tid)
{
    for (int i = tid; i < LS * LS; i += 256) {
        int r = i / LS, c = i - r * LS;
        int gr = oy0 + r; if (gr >= HH) gr -= HH;   // exact circular wrap
        int gc = ox0 + c; if (gc >= WW) gc -= WW;
        L[i] = img[gr * WW + gc];
    }
}

// diffsq fill: sq[r][c..c+1] = (L[r+4][c+4..] - L[shifted])^2, shift = scalar offset
__device__ __forceinline__ void fill_sq(const float* __restrict__ L, float* sq,
                                        int soff, const int* fsrc, const int* fdst, int fn)
{
#pragma unroll
    for (int k = 0; k < 3; ++k) {
        if (k < fn) {
            int s = fsrc[k];
            float a0 = L[s], a1 = L[s + 1];          // -> ds_read2_b32
            float b0 = L[s + soff], b1 = L[s + soff + 1];
            float d0 = a0 - b0, d1 = a1 - b1;
            *(float2*)&sq[fdst[k]] = make_float2(d0 * d0, d1 * d1);
        }
    }
}

#define G0 0.32465246735834974f   // exp(-9/8)
#define G1 0.6065306597126334f    // exp(-4/8)
#define G2 0.8824969025845955f    // exp(-1/8)
#define KS 0.039788735772973836f  // 1/(8*pi)

// horizontal 7-tap, 8 outputs per unit via register sliding window (152 units)
__device__ __forceinline__ void horiz_pass(const float* __restrict__ sq, float* tmp, int unit)
{
    int r = unit >> 2, c0 = (unit & 3) << 3;
    const float* s = &sq[r * SQLD + c0];
    float v[14];
#pragma unroll
    for (int t = 0; t < 7; ++t) {
        float2 p = *(const float2*)&s[2 * t];
        v[2 * t] = p.x; v[2 * t + 1] = p.y;
    }
    float* o = &tmp[r * TMLD + c0];
#pragma unroll
    for (int k = 0; k < 8; k += 2) {
        float r0 = fmaf(G0, v[k] + v[k + 6],
                   fmaf(G1, v[k + 1] + v[k + 5],
                   fmaf(G2, v[k + 2] + v[k + 4], v[k + 3])));
        float r1 = fmaf(G0, v[k + 1] + v[k + 7],
                   fmaf(G1, v[k + 2] + v[k + 6],
                   fmaf(G2, v[k + 3] + v[k + 5], v[k + 4])));
        *(float2*)&o[k] = make_float2(r0, r1);
    }
}

// vertical 7-tap, 4-row strip per thread via sliding window (10 reads -> 4 outputs)
__device__ __forceinline__ void vert_pass(const float* __restrict__ tmp, int x, int ry0, float* D)
{
    const float* t = &tmp[ry0 * TMLD + x];
    float v[10];
#pragma unroll
    for (int j = 0; j < 10; ++j) v[j] = t[j * TMLD];
#pragma unroll
    for (int k = 0; k < 4; ++k)
        D[k] = KS * fmaf(G0, v[k] + v[k + 6],
                    fmaf(G1, v[k + 1] + v[k + 5],
                    fmaf(G2, v[k + 2] + v[k + 4], v[k + 3])));
}

__device__ __forceinline__ void make_fill_idx(int tid, int* fsrc, int* fdst, int& fn)
{
    fn = 0;
#pragma unroll
    for (int k = 0; k < 3; ++k) {
        int u = tid + k * 256;
        if (u < NFU) {
            int r = u / 19, c2 = (u - r * 19) * 2;
            fsrc[fn] = (r + 4) * LS + (c2 + 4);
            fdst[fn] = r * SQLD + c2;
            ++fn;
        }
    }
}

// Stage 2: per (tile, batch, image): V = mean of 4 cardinal D + eps, minD over 99 shifts
extern "C" __global__ void __launch_bounds__(256, 4)
mind_stage2(const float* __restrict__ pred, const float* __restrict__ gt,
            float* __restrict__ ws)
{
    __shared__ __align__(16) float L[LS * LS];
    __shared__ __align__(16) float sq[FR * SQLD];
    __shared__ __align__(16) float tmp[FR * TMLD];
    const int tid = threadIdx.x;
    const int b = blockIdx.y, z = blockIdx.z;
    const int oy0 = ((int)blockIdx.x / NTILE) * TILE;
    const int ox0 = ((int)blockIdx.x % NTILE) * TILE;
    const float* img = (z ? gt : pred) + (size_t)b * HH * WW;

    load_img_tile(img, oy0, ox0, L, tid);
    int fsrc[3], fdst[3], fn;
    make_fill_idx(tid, fsrc, fdst, fn);
    const int x = tid & 31, ry0 = (tid >> 5) * 4;

    float dmin[4] = {1e30f, 1e30f, 1e30f, 1e30f};
    float vsum[4] = {0.f, 0.f, 0.f, 0.f};
    __syncthreads();

    for (int s = 0; s < NSHIFT; ++s) {
        int t = (s < 55) ? s : s + 1;           // skip (0,0)
        int sx = t / 10 - 5;
        int sy = t - (t / 10) * 10 - 5;
        int soff = -(sy * LS + sx);
        fill_sq(L, sq, soff, fsrc, fdst, fn);
        __syncthreads();
        if (tid < 152) horiz_pass(sq, tmp, tid);
        __syncthreads();
        float D[4];
        vert_pass(tmp, x, ry0, D);
        const bool card = (sx * sx + sy * sy) == 1;
#pragma unroll
        for (int k = 0; k < 4; ++k) {
            dmin[k] = fminf(dmin[k], D[k]);
            if (card) vsum[k] += D[k];
        }
    }

    float* V = ws + (size_t)z * NPIX;
    float* M = ws + (size_t)(2 + z) * NPIX;
#pragma unroll
    for (int k = 0; k < 4; ++k) {
        int oy = oy0 + ry0 + k, ox = ox0 + x;
        if (oy < OUTD && ox < OUTD) {
            size_t idx = ((size_t)b * OUTD + oy) * OUTD + ox;
            V[idx] = vsum[k] * 0.25f + 1e-5f;
            M[idx] = dmin[k];
        }
    }
}

// Stage 3: recompute D per shift for both images, accumulate |exp - exp|, atomicAdd mean
extern "C" __global__ void __launch_bounds__(256, 4)
mind_stage3(const float* __restrict__ pred, const float* __restrict__ gt,
            const float* __restrict__ ws, float* __restrict__ out)
{
    __shared__ __align__(16) float LP[LS * LS];
    __shared__ __align__(16) float LG[LS * LS];
    __shared__ __align__(16) float sqP[FR * SQLD];
    __shared__ __align__(16) float sqG[FR * SQLD];
    __shared__ __align__(16) float tmpP[FR * TMLD];
    __shared__ __align__(16) float tmpG[FR * TMLD];
    __shared__ float wred[4];
    const int tid = threadIdx.x;
    const int b = blockIdx.y, zh = blockIdx.z;     // zh = shift half
    const int oy0 = ((int)blockIdx.x / NTILE) * TILE;
    const int ox0 = ((int)blockIdx.x % NTILE) * TILE;
    const float* ip = pred + (size_t)b * HH * WW;
    const float* ig = gt + (size_t)b * HH * WW;

    load_img_tile(ip, oy0, ox0, LP, tid);
    load_img_tile(ig, oy0, ox0, LG, tid);
    int fsrc[3], fdst[3], fn;
    make_fill_idx(tid, fsrc, fdst, fn);
    const int x = tid & 31, ry0 = (tid >> 5) * 4;

    const float* Vp = ws;
    const float* Vg = ws + (size_t)NPIX;
    const float* Mp = ws + (size_t)2 * NPIX;
    const float* Mg = ws + (size_t)3 * NPIX;
    float rvp[4], rvg[4], mp[4], mg[4];
    bool valid[4];
#pragma unroll
    for (int k = 0; k < 4; ++k) {
        int oy = oy0 + ry0 + k, ox = ox0 + x;
        valid[k] = (oy < OUTD) && (ox < OUTD);
        if (valid[k]) {
            size_t idx = ((size_t)b * OUTD + oy) * OUTD + ox;
            rvp[k] = 1.0f / Vp[idx]; mp[k] = Mp[idx];
            rvg[k] = 1.0f / Vg[idx]; mg[k] = Mg[idx];
        } else {
            rvp[k] = 0.f; mp[k] = 0.f; rvg[k] = 0.f; mg[k] = 0.f;
        }
    }
    __syncthreads();

    const int s_beg = zh * 50;
    const int s_end = zh ? NSHIFT : 50;
    float acc = 0.f;
    for (int s = s_beg; s < s_end; ++s) {
        int t = (s < 55) ? s : s + 1;
        int sx = t / 10 - 5;
        int sy = t - (t / 10) * 10 - 5;
        int soff = -(sy * LS + sx);
        fill_sq(LP, sqP, soff, fsrc, fdst, fn);
        fill_sq(LG, sqG, soff, fsrc, fdst, fn);
        __syncthreads();
        if (tid < 152) horiz_pass(sqP, tmpP, tid);          // waves 0..2
        if (tid >= 104) horiz_pass(sqG, tmpG, tid - 104);   // waves 1..3
        __syncthreads();
        float Dp[4], Dg[4];
        vert_pass(tmpP, x, ry0, Dp);
        vert_pass(tmpG, x, ry0, Dg);
#pragma unroll
        for (int k = 0; k < 4; ++k) {
            if (valid[k]) {
                float ep = __expf((mp[k] - Dp[k]) * rvp[k]);
                float eg = __expf((mg[k] - Dg[k]) * rvg[k]);
                acc += fabsf(ep - eg);
            }
        }
    }

#pragma unroll
    for (int off = 32; off > 0; off >>= 1) acc += __shfl_down(acc, off, 64);
    const int lane = tid & 63, wv = tid >> 6;
    if (lane == 0) wred[wv] = acc;
    __syncthreads();
    if (tid == 0) {
        const float SC = (float)(1.0 / 54212400.0);  // 1/(4*370*370*99)
        atomicAdd(out, (wred[0] + wred[1] + wred[2] + wred[3]) * SC);
    }
}

extern "C" void kernel_launch(void* const* d_in, const int* in_sizes, int n_in,
                              void* d_out, int out_size, void* d_ws, size_t ws_size,
                              hipStream_t stream)
{
    (void)in_sizes; (void)n_in; (void)out_size; (void)ws_size;
    const float* pred = (const float*)d_in[0];
    const float* gt   = (const float*)d_in[1];
    float* out = (float*)d_out;
    float* ws  = (float*)d_ws;

    hipMemsetAsync(d_out, 0, sizeof(float), stream);

    dim3 g2(NTILE * NTILE, 4, 2);
    mind_stage2<<<g2, 256, 0, stream>>>(pred, gt, ws);
    dim3 g3(NTILE * NTILE, 4, 2);
    mind_stage3<<<g3, 256, 0, stream>>>(pred, gt, ws, out);
}

// Round 3
// 337.550 us; speedup vs baseline: 2.2552x; 1.0781x over previous
//
#include <hip/hip_runtime.h>

#define HH 384
#define WW 384
#define OUTD 370
#define TILE 32
#define NTILE 12
#define LS 47            // image LDS tile extent and stride (odd -> bank-safe)
#define FR 38            // diffsq fill extent (TILE + 6 conv halo)
#define SQLD 41          // sq stride: ODD -> mixed-parity banks, ~2-way max (free)
#define TMLD 33          // tmp stride: ODD -> residue r+c, exactly 2-way (free)
#define NPIX (4 * OUTD * OUTD)
#define NSHIFT 99
#define NFU 722          // fill pair units: 38*38/2

#define G0 0.32465246735834974f   // exp(-9/8)
#define G1 0.6065306597126334f    // exp(-4/8)
#define G2 0.8824969025845955f    // exp(-1/8)
#define KS 0.039788735772973836f  // 1/(8*pi)

__device__ __forceinline__ void load_img_tile(const float* __restrict__ img,
                                              int oy0, int ox0, float* L, int tid)
{
    for (int i = tid; i < LS * LS; i += 256) {
        int r = i / LS, c = i - r * LS;
        int gr = oy0 + r; if (gr >= HH) gr -= HH;   // exact circular wrap
        int gc = ox0 + c; if (gc >= WW) gc -= WW;
        L[i] = img[gr * WW + gc];
    }
}

__device__ __forceinline__ void make_fill_idx(int tid, int* fsrc, int* fdst, int& fn)
{
    fn = 0;
#pragma unroll
    for (int k = 0; k < 3; ++k) {
        int u = tid + k * 256;
        if (u < NFU) {
            int r = u / 19, c2 = (u - r * 19) * 2;
            fsrc[fn] = (r + 4) * LS + (c2 + 4);
            fdst[fn] = r * SQLD + c2;
            ++fn;
        }
    }
}

// loop-invariant center pair -> registers (read once, reused for all 99 shifts)
__device__ __forceinline__ void preload_a(const float* __restrict__ L,
                                          const int* fsrc, int fn, float2* a)
{
#pragma unroll
    for (int k = 0; k < 3; ++k)
        if (k < fn) a[k] = make_float2(L[fsrc[k]], L[fsrc[k] + 1]);
}

// diffsq fill: sq[dst..dst+1] = (a - L[shifted])^2; shift enters as scalar offset
__device__ __forceinline__ void fill_sq(const float* __restrict__ L, float* sq,
                                        int soff, const int* fsrc, const int* fdst,
                                        int fn, const float2* a)
{
#pragma unroll
    for (int k = 0; k < 3; ++k) {
        if (k < fn) {
            int s = fsrc[k] + soff;
            float b0 = L[s], b1 = L[s + 1];          // -> ds_read2_b32
            float d0 = a[k].x - b0, d1 = a[k].y - b1;
            sq[fdst[k]] = d0 * d0;                   // -> ds_write2_b32
            sq[fdst[k] + 1] = d1 * d1;
        }
    }
}

// horizontal 7-tap, 8 outputs per unit via register sliding window (152 units)
__device__ __forceinline__ void horiz_pass(const float* __restrict__ sq, float* tmp, int unit)
{
    int r = unit >> 2, c0 = (unit & 3) << 3;
    const float* s = &sq[r * SQLD + c0];
    float v[14];
#pragma unroll
    for (int t = 0; t < 14; ++t) v[t] = s[t];        // -> 7x ds_read2_b32
    float* o = &tmp[r * TMLD + c0];
#pragma unroll
    for (int k = 0; k < 8; ++k)
        o[k] = fmaf(G0, v[k] + v[k + 6],
               fmaf(G1, v[k + 1] + v[k + 5],
               fmaf(G2, v[k + 2] + v[k + 4], v[k + 3])));
}

// vertical 7-tap, 4-row strip per thread via sliding window (10 reads -> 4 outputs)
__device__ __forceinline__ void vert_pass(const float* __restrict__ tmp, int x, int ry0, float* D)
{
    const float* t = &tmp[ry0 * TMLD + x];
    float v[10];
#pragma unroll
    for (int j = 0; j < 10; ++j) v[j] = t[j * TMLD];
#pragma unroll
    for (int k = 0; k < 4; ++k)
        D[k] = KS * fmaf(G0, v[k] + v[k + 6],
                    fmaf(G1, v[k + 1] + v[k + 5],
                    fmaf(G2, v[k + 2] + v[k + 4], v[k + 3])));
}

// Stage 2: per (tile, batch, image): V = mean of 4 cardinal D + eps, minD over 99 shifts
extern "C" __global__ void __launch_bounds__(256, 4)
mind_stage2(const float* __restrict__ pred, const float* __restrict__ gt,
            float* __restrict__ ws)
{
    __shared__ float L[LS * LS];
    __shared__ float sq[FR * SQLD];
    __shared__ float tmp[FR * TMLD];
    const int tid = threadIdx.x;
    const int b = blockIdx.y, z = blockIdx.z;
    const int oy0 = ((int)blockIdx.x / NTILE) * TILE;
    const int ox0 = ((int)blockIdx.x % NTILE) * TILE;
    const float* img = (z ? gt : pred) + (size_t)b * HH * WW;

    load_img_tile(img, oy0, ox0, L, tid);
    int fsrc[3], fdst[3], fn;
    make_fill_idx(tid, fsrc, fdst, fn);
    const int x = tid & 31, ry0 = (tid >> 5) * 4;

    float dmin[4] = {1e30f, 1e30f, 1e30f, 1e30f};
    float vsum[4] = {0.f, 0.f, 0.f, 0.f};
    __syncthreads();
    float2 a[3];
    preload_a(L, fsrc, fn, a);

    for (int s = 0; s < NSHIFT; ++s) {
        int t = (s < 55) ? s : s + 1;           // skip (0,0)
        int sx = t / 10 - 5;
        int sy = t - (t / 10) * 10 - 5;
        int soff = -(sy * LS + sx);
        fill_sq(L, sq, soff, fsrc, fdst, fn, a);
        __syncthreads();
        if (tid < 152) horiz_pass(sq, tmp, tid);
        __syncthreads();
        float D[4];
        vert_pass(tmp, x, ry0, D);
        const bool card = (sx * sx + sy * sy) == 1;
#pragma unroll
        for (int k = 0; k < 4; ++k) {
            dmin[k] = fminf(dmin[k], D[k]);
            if (card) vsum[k] += D[k];
        }
    }

    float* V = ws + (size_t)z * NPIX;
    float* M = ws + (size_t)(2 + z) * NPIX;
#pragma unroll
    for (int k = 0; k < 4; ++k) {
        int oy = oy0 + ry0 + k, ox = ox0 + x;
        if (oy < OUTD && ox < OUTD) {
            size_t idx = ((size_t)b * OUTD + oy) * OUTD + ox;
            V[idx] = vsum[k] * 0.25f + 1e-5f;
            M[idx] = dmin[k];
        }
    }
}

// Stage 3: recompute D per shift for both images, accumulate |exp - exp|, atomicAdd mean
extern "C" __global__ void __launch_bounds__(256, 4)
mind_stage3(const float* __restrict__ pred, const float* __restrict__ gt,
            const float* __restrict__ ws, float* __restrict__ out)
{
    __shared__ float LP[LS * LS];
    __shared__ float LG[LS * LS];
    __shared__ float sqP[FR * SQLD];
    __shared__ float sqG[FR * SQLD];
    __shared__ float tmpP[FR * TMLD];
    __shared__ float tmpG[FR * TMLD];
    __shared__ float wred[4];
    const int tid = threadIdx.x;
    const int b = blockIdx.y, zh = blockIdx.z;     // zh = shift half
    const int oy0 = ((int)blockIdx.x / NTILE) * TILE;
    const int ox0 = ((int)blockIdx.x % NTILE) * TILE;
    const float* ip = pred + (size_t)b * HH * WW;
    const float* ig = gt + (size_t)b * HH * WW;

    load_img_tile(ip, oy0, ox0, LP, tid);
    load_img_tile(ig, oy0, ox0, LG, tid);
    int fsrc[3], fdst[3], fn;
    make_fill_idx(tid, fsrc, fdst, fn);
    const int x = tid & 31, ry0 = (tid >> 5) * 4;

    const float* Vp = ws;
    const float* Vg = ws + (size_t)NPIX;
    const float* Mp = ws + (size_t)2 * NPIX;
    const float* Mg = ws + (size_t)3 * NPIX;
    float rvp[4], rvg[4], mp[4], mg[4];
    bool valid[4];
#pragma unroll
    for (int k = 0; k < 4; ++k) {
        int oy = oy0 + ry0 + k, ox = ox0 + x;
        valid[k] = (oy < OUTD) && (ox < OUTD);
        if (valid[k]) {
            size_t idx = ((size_t)b * OUTD + oy) * OUTD + ox;
            rvp[k] = 1.0f / Vp[idx]; mp[k] = Mp[idx];
            rvg[k] = 1.0f / Vg[idx]; mg[k] = Mg[idx];
        } else {
            rvp[k] = 0.f; mp[k] = 0.f; rvg[k] = 0.f; mg[k] = 0.f;
        }
    }
    __syncthreads();
    float2 aP[3], aG[3];
    preload_a(LP, fsrc, fn, aP);
    preload_a(LG, fsrc, fn, aG);

    const int s_beg = zh * 50;
    const int s_end = zh ? NSHIFT : 50;
    float acc = 0.f;
    for (int s = s_beg; s < s_end; ++s) {
        int t = (s < 55) ? s : s + 1;
        int sx = t / 10 - 5;
        int sy = t - (t / 10) * 10 - 5;
        int soff = -(sy * LS + sx);
        fill_sq(LP, sqP, soff, fsrc, fdst, fn, aP);
        fill_sq(LG, sqG, soff, fsrc, fdst, fn, aG);
        __syncthreads();
        if (tid < 152) horiz_pass(sqP, tmpP, tid);          // waves 0..2
        if (tid >= 104) horiz_pass(sqG, tmpG, tid - 104);   // waves 1..3
        __syncthreads();
        float Dp[4], Dg[4];
        vert_pass(tmpP, x, ry0, Dp);
        vert_pass(tmpG, x, ry0, Dg);
#pragma unroll
        for (int k = 0; k < 4; ++k) {
            if (valid[k]) {
                float ep = __expf((mp[k] - Dp[k]) * rvp[k]);
                float eg = __expf((mg[k] - Dg[k]) * rvg[k]);
                acc += fabsf(ep - eg);
            }
        }
    }

#pragma unroll
    for (int off = 32; off > 0; off >>= 1) acc += __shfl_down(acc, off, 64);
    const int lane = tid & 63, wv = tid >> 6;
    if (lane == 0) wred[wv] = acc;
    __syncthreads();
    if (tid == 0) {
        const float SC = (float)(1.0 / 54212400.0);  // 1/(4*370*370*99)
        atomicAdd(out, (wred[0] + wred[1] + wred[2] + wred[3]) * SC);
    }
}

extern "C" void kernel_launch(void* const* d_in, const int* in_sizes, int n_in,
                              void* d_out, int out_size, void* d_ws, size_t ws_size,
                              hipStream_t stream)
{
    (void)in_sizes; (void)n_in; (void)out_size; (void)ws_size;
    const float* pred = (const float*)d_in[0];
    const float* gt   = (const float*)d_in[1];
    float* out = (float*)d_out;
    float* ws  = (float*)d_ws;

    hipMemsetAsync(d_out, 0, sizeof(float), stream);

    dim3 g2(NTILE * NTILE, 4, 2);
    mind_stage2<<<g2, 256, 0, stream>>>(pred, gt, ws);
    dim3 g3(NTILE * NTILE, 4, 2);
    mind_stage3<<<g3, 256, 0, stream>>>(pred, gt, ws, out);
}

// Round 4
// 307.510 us; speedup vs baseline: 2.4755x; 1.0977x over previous
//
#include <hip/hip_runtime.h>

#define HH 384
#define WW 384
#define OUTD 370
#define TILE 32
#define NTILE 12
#define LS 47            // image LDS tile extent and stride (odd -> bank-safe)
#define FR 38            // diffsq fill extent (TILE + 6 conv halo)
#define SQLD 44          // sq stride: 44*4=176B = 11*16 -> rows 16B-aligned for b128 reads;
                         // residue 12r+c0 with c0 in {0,8,16,24} -> exact 2-way (free)
#define TMLD 39          // tmp_T stride (transposed: [col][row]), odd -> 2-way max
#define NPIX (4 * OUTD * OUTD)
#define NSHIFT 99
#define NFU 722          // fill pair units: 38*38/2

#define G0 0.32465246735834974f   // exp(-9/8)
#define G1 0.6065306597126334f    // exp(-4/8)
#define G2 0.8824969025845955f    // exp(-1/8)
#define KS 0.039788735772973836f  // 1/(8*pi)

__device__ __forceinline__ void load_img_tile(const float* __restrict__ img,
                                              int oy0, int ox0, float* L, int tid)
{
    for (int i = tid; i < LS * LS; i += 256) {
        int r = i / LS, c = i - r * LS;
        int gr = oy0 + r; if (gr >= HH) gr -= HH;   // exact circular wrap
        int gc = ox0 + c; if (gc >= WW) gc -= WW;
        L[i] = img[gr * WW + gc];
    }
}

__device__ __forceinline__ void make_fill_idx(int tid, int* fsrc, int* fdst, int& fn)
{
    fn = 0;
#pragma unroll
    for (int k = 0; k < 3; ++k) {
        int u = tid + k * 256;
        if (u < NFU) {
            int r = u / 19, c2 = (u - r * 19) * 2;
            fsrc[fn] = (r + 4) * LS + (c2 + 4);
            fdst[fn] = r * SQLD + c2;
            ++fn;
        }
    }
}

// loop-invariant center pair -> registers (read once, reused for all 99 shifts)
__device__ __forceinline__ void preload_a(const float* __restrict__ L,
                                          const int* fsrc, int fn, float2* a)
{
#pragma unroll
    for (int k = 0; k < 3; ++k)
        if (k < fn) a[k] = make_float2(L[fsrc[k]], L[fsrc[k] + 1]);
}

// diffsq fill: sq[dst..dst+1] = (a - L[shifted])^2; shift enters as scalar offset
__device__ __forceinline__ void fill_sq(const float* __restrict__ L, float* sq,
                                        int soff, const int* fsrc, const int* fdst,
                                        int fn, const float2* a)
{
#pragma unroll
    for (int k = 0; k < 3; ++k) {
        if (k < fn) {
            int s = fsrc[k] + soff;
            float b0 = L[s], b1 = L[s + 1];          // -> ds_read2_b32
            float d0 = a[k].x - b0, d1 = a[k].y - b1;
            sq[fdst[k]] = d0 * d0;                   // -> ds_write2_b32 (dense, ~2-way)
            sq[fdst[k] + 1] = d1 * d1;
        }
    }
}

// horizontal 7-tap, 8 outputs per unit; b128-vectorized reads, TRANSPOSED writes
__device__ __forceinline__ void horiz_pass(const float* __restrict__ sq, float* tmpT, int unit)
{
    int r = unit >> 2, c0 = (unit & 3) << 3;
    const float* s = &sq[r * SQLD + c0];             // 16B-aligned
    float4 A = *(const float4*)s;
    float4 B = *(const float4*)(s + 4);
    float4 C = *(const float4*)(s + 8);
    float2 E = *(const float2*)(s + 12);
    float v[14] = {A.x, A.y, A.z, A.w, B.x, B.y, B.z, B.w,
                   C.x, C.y, C.z, C.w, E.x, E.y};
    float* o = &tmpT[c0 * TMLD + r];                 // tmp_T[col][row]
#pragma unroll
    for (int k = 0; k < 8; ++k)
        o[k * TMLD] = fmaf(G0, v[k] + v[k + 6],
                      fmaf(G1, v[k + 1] + v[k + 5],
                      fmaf(G2, v[k + 2] + v[k + 4], v[k + 3])));
}

// vertical 7-tap from transposed tmp: 10 CONSECUTIVE reads -> 5x ds_read2_b32
__device__ __forceinline__ void vert_pass(const float* __restrict__ tmpT, int x, int ry0, float* D)
{
    const float* t = &tmpT[x * TMLD + ry0];
    float v[10];
#pragma unroll
    for (int j = 0; j < 10; ++j) v[j] = t[j];
#pragma unroll
    for (int k = 0; k < 4; ++k)
        D[k] = KS * fmaf(G0, v[k] + v[k + 6],
                    fmaf(G1, v[k + 1] + v[k + 5],
                    fmaf(G2, v[k + 2] + v[k + 4], v[k + 3])));
}

__device__ __forceinline__ void shift_of(int s, int& sx, int& sy)
{
    int t = (s < 55) ? s : s + 1;    // skip (0,0)
    sx = t / 10 - 5;
    sy = t - (t / 10) * 10 - 5;
}

// Stage 2: per (tile, batch, image): V = mean of 4 cardinal D + eps, minD over 99 shifts
extern "C" __global__ void __launch_bounds__(256, 6)
mind_stage2(const float* __restrict__ pred, const float* __restrict__ gt,
            float* __restrict__ ws)
{
    __shared__ __align__(16) float L[LS * LS];
    __shared__ __align__(16) float sq[FR * SQLD];
    __shared__ __align__(16) float tmpT[TILE * TMLD];
    const int tid = threadIdx.x;
    const int b = blockIdx.y, z = blockIdx.z;
    const int oy0 = ((int)blockIdx.x / NTILE) * TILE;
    const int ox0 = ((int)blockIdx.x % NTILE) * TILE;
    const float* img = (z ? gt : pred) + (size_t)b * HH * WW;

    load_img_tile(img, oy0, ox0, L, tid);
    int fsrc[3], fdst[3], fn;
    make_fill_idx(tid, fsrc, fdst, fn);
    const int x = tid & 31, ry0 = (tid >> 5) * 4;

    float dmin[4] = {1e30f, 1e30f, 1e30f, 1e30f};
    float vsum[4] = {0.f, 0.f, 0.f, 0.f};
    __syncthreads();
    float2 a[3];
    preload_a(L, fsrc, fn, a);

    {   // prologue fill for shift 0
        int sx, sy; shift_of(0, sx, sy);
        fill_sq(L, sq, -(sy * LS + sx), fsrc, fdst, fn, a);
    }
    for (int s = 0; s < NSHIFT; ++s) {
        int sx, sy; shift_of(s, sx, sy);
        __syncthreads();
        if (tid < 152) horiz_pass(sq, tmpT, tid);
        __syncthreads();
        float D[4];
        vert_pass(tmpT, x, ry0, D);
        const bool card = (sx * sx + sy * sy) == 1;
#pragma unroll
        for (int k = 0; k < 4; ++k) {
            dmin[k] = fminf(dmin[k], D[k]);
            if (card) vsum[k] += D[k];
        }
        if (s + 1 < NSHIFT) {                       // fill(s+1): sq free after horiz
            int nx, ny; shift_of(s + 1, nx, ny);
            fill_sq(L, sq, -(ny * LS + nx), fsrc, fdst, fn, a);
        }
    }

    float* V = ws + (size_t)z * NPIX;
    float* M = ws + (size_t)(2 + z) * NPIX;
#pragma unroll
    for (int k = 0; k < 4; ++k) {
        int oy = oy0 + ry0 + k, ox = ox0 + x;
        if (oy < OUTD && ox < OUTD) {
            size_t idx = ((size_t)b * OUTD + oy) * OUTD + ox;
            V[idx] = vsum[k] * 0.25f + 1e-5f;
            M[idx] = dmin[k];
        }
    }
}

// Stage 3: recompute D per shift for both images (serialized through ONE sq/tmp ->
// 29.4KB LDS -> 5 blocks/CU), accumulate |exp - exp|, atomicAdd mean
extern "C" __global__ void __launch_bounds__(256, 5)
mind_stage3(const float* __restrict__ pred, const float* __restrict__ gt,
            const float* __restrict__ ws, float* __restrict__ out)
{
    __shared__ __align__(16) float LP[LS * LS];
    __shared__ __align__(16) float LG[LS * LS];
    __shared__ __align__(16) float sq[FR * SQLD];
    __shared__ __align__(16) float tmpT[TILE * TMLD];
    __shared__ float wred[4];
    const int tid = threadIdx.x;
    const int b = blockIdx.y, zh = blockIdx.z;     // zh = shift half
    const int oy0 = ((int)blockIdx.x / NTILE) * TILE;
    const int ox0 = ((int)blockIdx.x % NTILE) * TILE;
    const float* ip = pred + (size_t)b * HH * WW;
    const float* ig = gt + (size_t)b * HH * WW;

    load_img_tile(ip, oy0, ox0, LP, tid);
    load_img_tile(ig, oy0, ox0, LG, tid);
    int fsrc[3], fdst[3], fn;
    make_fill_idx(tid, fsrc, fdst, fn);
    const int x = tid & 31, ry0 = (tid >> 5) * 4;

    const float* Vp = ws;
    const float* Vg = ws + (size_t)NPIX;
    const float* Mp = ws + (size_t)2 * NPIX;
    const float* Mg = ws + (size_t)3 * NPIX;
    float rvp[4], rvg[4], mp[4], mg[4];
    bool valid[4];
#pragma unroll
    for (int k = 0; k < 4; ++k) {
        int oy = oy0 + ry0 + k, ox = ox0 + x;
        valid[k] = (oy < OUTD) && (ox < OUTD);
        if (valid[k]) {
            size_t idx = ((size_t)b * OUTD + oy) * OUTD + ox;
            rvp[k] = 1.0f / Vp[idx]; mp[k] = Mp[idx];
            rvg[k] = 1.0f / Vg[idx]; mg[k] = Mg[idx];
        } else {
            rvp[k] = 0.f; mp[k] = 0.f; rvg[k] = 0.f; mg[k] = 0.f;
        }
    }
    __syncthreads();
    float2 aP[3], aG[3];
    preload_a(LP, fsrc, fn, aP);
    preload_a(LG, fsrc, fn, aG);

    const int s_beg = zh * 50;
    const int s_end = zh ? NSHIFT : 50;
    float acc = 0.f;

    {   // prologue: fill P for first shift
        int sx, sy; shift_of(s_beg, sx, sy);
        fill_sq(LP, sq, -(sy * LS + sx), fsrc, fdst, fn, aP);
    }
    for (int s = s_beg; s < s_end; ++s) {
        int sx, sy; shift_of(s, sx, sy);
        int soff = -(sy * LS + sx);
        __syncthreads();                            // b1: fillP done
        if (tid < 152) horiz_pass(sq, tmpT, tid);
        __syncthreads();                            // b2: tmpT(P) ready, sq free
        float Dp[4];
        vert_pass(tmpT, x, ry0, Dp);
        fill_sq(LG, sq, soff, fsrc, fdst, fn, aG);  // overlaps vertP (disjoint bufs)
        __syncthreads();                            // b3: fillG done, tmpT free
        if (tid < 152) horiz_pass(sq, tmpT, tid);
        __syncthreads();                            // b4: tmpT(G) ready, sq free
        float Dg[4];
        vert_pass(tmpT, x, ry0, Dg);
#pragma unroll
        for (int k = 0; k < 4; ++k) {
            if (valid[k]) {
                float ep = __expf((mp[k] - Dp[k]) * rvp[k]);
                float eg = __expf((mg[k] - Dg[k]) * rvg[k]);
                acc += fabsf(ep - eg);
            }
        }
        if (s + 1 < s_end) {                        // fillP(s+1) overlaps vertG
            int nx, ny; shift_of(s + 1, nx, ny);
            fill_sq(LP, sq, -(ny * LS + nx), fsrc, fdst, fn, aP);
        }
    }

#pragma unroll
    for (int off = 32; off > 0; off >>= 1) acc += __shfl_down(acc, off, 64);
    const int lane = tid & 63, wv = tid >> 6;
    if (lane == 0) wred[wv] = acc;
    __syncthreads();
    if (tid == 0) {
        const float SC = (float)(1.0 / 54212400.0);  // 1/(4*370*370*99)
        atomicAdd(out, (wred[0] + wred[1] + wred[2] + wred[3]) * SC);
    }
}

extern "C" void kernel_launch(void* const* d_in, const int* in_sizes, int n_in,
                              void* d_out, int out_size, void* d_ws, size_t ws_size,
                              hipStream_t stream)
{
    (void)in_sizes; (void)n_in; (void)out_size; (void)ws_size;
    const float* pred = (const float*)d_in[0];
    const float* gt   = (const float*)d_in[1];
    float* out = (float*)d_out;
    float* ws  = (float*)d_ws;

    hipMemsetAsync(d_out, 0, sizeof(float), stream);

    dim3 g2(NTILE * NTILE, 4, 2);
    mind_stage2<<<g2, 256, 0, stream>>>(pred, gt, ws);
    dim3 g3(NTILE * NTILE, 4, 2);
    mind_stage3<<<g3, 256, 0, stream>>>(pred, gt, ws, out);
}

// Round 5
// 244.342 us; speedup vs baseline: 3.1155x; 1.2585x over previous
//
#include <hip/hip_runtime.h>

#define HH 384
#define WW 384
#define OUTD 370
#define TILE 32
#define NTILE 12
#define LS 47            // image LDS tile extent and stride (odd -> bank-safe)
#define TMLD 39          // tmp_T stride (transposed [col][row]); write residue 7c0+r+7k
                         // and read residue 7x+ry0 each hit every bank exactly 2x (free)
#define NPIX (4 * OUTD * OUTD)
#define NSHIFT 99

#define G0 0.32465246735834974f   // exp(-9/8)
#define G1 0.6065306597126334f    // exp(-4/8)
#define G2 0.8824969025845955f    // exp(-1/8)
#define KS 0.039788735772973836f  // 1/(8*pi)

__device__ __forceinline__ void load_img_tile(const float* __restrict__ img,
                                              int oy0, int ox0, float* L, int tid)
{
    for (int i = tid; i < LS * LS; i += 256) {
        int r = i / LS, c = i - r * LS;
        int gr = oy0 + r; if (gr >= HH) gr -= HH;   // exact circular wrap
        int gc = ox0 + c; if (gc >= WW) gc -= WW;
        L[i] = img[gr * WW + gc];
    }
}

__device__ __forceinline__ void shift_of(int s, int& sx, int& sy)
{
    int t = (s < 55) ? s : s + 1;    // skip (0,0)
    sx = t / 10 - 5;
    sy = t - (t / 10) * 10 - 5;
}

__device__ __forceinline__ float tap7(const float* v)
{
    return fmaf(G0, v[0] + v[6],
           fmaf(G1, v[1] + v[5],
           fmaf(G2, v[2] + v[4], v[3])));
}

// horizontal 7-tap over diff^2 formed INLINE from L (no sq buffer):
// center window cA is loop-invariant (registers); shifted window = 7x ds_read2.
// 8 outputs, written transposed into tmp_T[col][row].
__device__ __forceinline__ void horiz8(const float* __restrict__ Lb,
                                       const float* __restrict__ cA,
                                       float* __restrict__ tb,
                                       int r, int c0, int sx, int sy)
{
    const float* Ls = &Lb[(r + 4 - sy) * LS + (c0 + 4 - sx)];
    float v[14];
#pragma unroll
    for (int t = 0; t < 14; ++t) { float d = cA[t] - Ls[t]; v[t] = d * d; }
    float* o = &tb[c0 * TMLD + r];
#pragma unroll
    for (int k = 0; k < 8; ++k) o[k * TMLD] = tap7(v + k);
}

// vertical 7-tap from transposed tmp: consecutive reads -> ds_read2
__device__ __forceinline__ void vert4(const float* __restrict__ tT, int x, int ry0, float* D)
{
    const float* t = &tT[x * TMLD + ry0];
    float w[10];
#pragma unroll
    for (int j = 0; j < 10; ++j) w[j] = t[j];
#pragma unroll
    for (int k = 0; k < 4; ++k) D[k] = KS * tap7(w + k);
}

// Stage 2: per (tile, batch, image): V = mean of 4 cardinal D + eps, minD over 99 shifts.
// Double-buffered tmpT -> ONE barrier per shift.
extern "C" __global__ void __launch_bounds__(256, 6)
mind_stage2(const float* __restrict__ pred, const float* __restrict__ gt,
            float* __restrict__ ws)
{
    __shared__ float L[LS * LS];
    __shared__ float tT[2][TILE * TMLD];
    const int tid = threadIdx.x;
    const int b = blockIdx.y, z = blockIdx.z;
    const int oy0 = ((int)blockIdx.x / NTILE) * TILE;
    const int ox0 = ((int)blockIdx.x % NTILE) * TILE;
    const float* img = (z ? gt : pred) + (size_t)b * HH * WW;

    load_img_tile(img, oy0, ox0, L, tid);
    const int hr = tid >> 2, hc0 = (tid & 3) << 3;   // horiz unit (tid<152)
    const int x = tid & 31, ry0 = (tid >> 5) * 8;    // vert-8 strip (tid<128)
    __syncthreads();

    float cA[14];
    if (tid < 152) {
        const float* p = &L[(hr + 4) * LS + hc0 + 4];
#pragma unroll
        for (int t = 0; t < 14; ++t) cA[t] = p[t];
    }

    float dmin[8], vsum[8];
#pragma unroll
    for (int k = 0; k < 8; ++k) { dmin[k] = 1e30f; vsum[k] = 0.f; }

    for (int s = 0; s < NSHIFT; ++s) {
        int sx, sy; shift_of(s, sx, sy);
        if (tid < 152) horiz8(L, cA, tT[s & 1], hr, hc0, sx, sy);
        __syncthreads();   // tT[s&1] ready; also separates vert(s-1) from horiz(s+1) writes
        if (tid < 128) {
            const float* t = &tT[s & 1][x * TMLD + ry0];
            float w[14];
#pragma unroll
            for (int j = 0; j < 14; ++j) w[j] = t[j];
            const bool card = (sx * sx + sy * sy) == 1;
#pragma unroll
            for (int k = 0; k < 8; ++k) {
                float D = KS * tap7(w + k);
                dmin[k] = fminf(dmin[k], D);
                if (card) vsum[k] += D;
            }
        }
    }

    if (tid < 128) {
        float* V = ws + (size_t)z * NPIX;
        float* M = ws + (size_t)(2 + z) * NPIX;
#pragma unroll
        for (int k = 0; k < 8; ++k) {
            int oy = oy0 + ry0 + k, ox = ox0 + x;
            if (oy < OUTD && ox < OUTD) {
                size_t idx = ((size_t)b * OUTD + oy) * OUTD + ox;
                V[idx] = vsum[k] * 0.25f + 1e-5f;
                M[idx] = dmin[k];
            }
        }
    }
}

// Stage 3: recompute D per shift for both images, accumulate |exp - exp|, atomicAdd mean.
// Horiz uses a combined 304-unit space (P:0..151, G:152..303) with pointer-selected
// image -> branchless; pass A = all 256 threads, pass B = threads 0..47.
extern "C" __global__ void __launch_bounds__(256, 5)
mind_stage3(const float* __restrict__ pred, const float* __restrict__ gt,
            const float* __restrict__ ws, float* __restrict__ out)
{
    __shared__ float LP[LS * LS];
    __shared__ float LG[LS * LS];
    __shared__ float tTP[TILE * TMLD];
    __shared__ float tTG[TILE * TMLD];
    __shared__ float wred[4];
    const int tid = threadIdx.x;
    const int b = blockIdx.y, zh = blockIdx.z;       // zh = shift half
    const int oy0 = ((int)blockIdx.x / NTILE) * TILE;
    const int ox0 = ((int)blockIdx.x % NTILE) * TILE;

    load_img_tile(pred + (size_t)b * HH * WW, oy0, ox0, LP, tid);
    load_img_tile(gt   + (size_t)b * HH * WW, oy0, ox0, LG, tid);

    // combined horiz unit decode
    const int cuA = tid;                 // P units 0..151, G units 0..103
    const bool gA = cuA >= 152;
    const int uA = cuA - (gA ? 152 : 0);
    const int rA = uA >> 2, cA0 = (uA & 3) << 3;
    const float* LbA = gA ? LG : LP;
    float* tbA = gA ? tTG : tTP;

    const bool hasB = tid < 48;          // G units 104..151
    const int uB = tid + 104;
    const int rB = uB >> 2, cB0 = (uB & 3) << 3;

    const int x = tid & 31, ry0 = (tid >> 5) * 4;

    const float* Vp = ws;
    const float* Vg = ws + (size_t)NPIX;
    const float* Mp = ws + (size_t)2 * NPIX;
    const float* Mg = ws + (size_t)3 * NPIX;
    float rvp[4], rvg[4], mp[4], mg[4];
    bool valid[4];
#pragma unroll
    for (int k = 0; k < 4; ++k) {
        int oy = oy0 + ry0 + k, ox = ox0 + x;
        valid[k] = (oy < OUTD) && (ox < OUTD);
        if (valid[k]) {
            size_t idx = ((size_t)b * OUTD + oy) * OUTD + ox;
            rvp[k] = 1.0f / Vp[idx]; mp[k] = Mp[idx];
            rvg[k] = 1.0f / Vg[idx]; mg[k] = Mg[idx];
        } else {
            rvp[k] = 0.f; mp[k] = 0.f; rvg[k] = 0.f; mg[k] = 0.f;
        }
    }
    __syncthreads();

    float cWA[14], cWB[14];
    {
        const float* p = &LbA[(rA + 4) * LS + cA0 + 4];
#pragma unroll
        for (int t = 0; t < 14; ++t) cWA[t] = p[t];
    }
    if (hasB) {
        const float* p = &LG[(rB + 4) * LS + cB0 + 4];
#pragma unroll
        for (int t = 0; t < 14; ++t) cWB[t] = p[t];
    }

    const int s_beg = zh * 50;
    const int s_end = zh ? NSHIFT : 50;
    float acc = 0.f;

    for (int s = s_beg; s < s_end; ++s) {
        int sx, sy; shift_of(s, sx, sy);
        horiz8(LbA, cWA, tbA, rA, cA0, sx, sy);
        if (hasB) horiz8(LG, cWB, tTG, rB, cB0, sx, sy);
        __syncthreads();                  // tTP/tTG ready
        float Dp[4], Dg[4];
        vert4(tTP, x, ry0, Dp);
        vert4(tTG, x, ry0, Dg);
#pragma unroll
        for (int k = 0; k < 4; ++k) {
            if (valid[k]) {
                float ep = __expf((mp[k] - Dp[k]) * rvp[k]);
                float eg = __expf((mg[k] - Dg[k]) * rvg[k]);
                acc += fabsf(ep - eg);
            }
        }
        __syncthreads();                  // vert done before next horiz overwrites
    }

#pragma unroll
    for (int off = 32; off > 0; off >>= 1) acc += __shfl_down(acc, off, 64);
    const int lane = tid & 63, wv = tid >> 6;
    if (lane == 0) wred[wv] = acc;
    __syncthreads();
    if (tid == 0) {
        const float SC = (float)(1.0 / 54212400.0);  // 1/(4*370*370*99)
        atomicAdd(out, (wred[0] + wred[1] + wred[2] + wred[3]) * SC);
    }
}

extern "C" void kernel_launch(void* const* d_in, const int* in_sizes, int n_in,
                              void* d_out, int out_size, void* d_ws, size_t ws_size,
                              hipStream_t stream)
{
    (void)in_sizes; (void)n_in; (void)out_size; (void)ws_size;
    const float* pred = (const float*)d_in[0];
    const float* gt   = (const float*)d_in[1];
    float* out = (float*)d_out;
    float* ws  = (float*)d_ws;

    hipMemsetAsync(d_out, 0, sizeof(float), stream);

    dim3 g2(NTILE * NTILE, 4, 2);
    mind_stage2<<<g2, 256, 0, stream>>>(pred, gt, ws);
    dim3 g3(NTILE * NTILE, 4, 2);
    mind_stage3<<<g3, 256, 0, stream>>>(pred, gt, ws, out);
}